// Round 2
// baseline (779.645 us; speedup 1.0000x reference)
//
#include <hip/hip_runtime.h>

#define TOKENS 2048
#define HIDDEN 2048
#define INTER  768
#define NEXP   16
#define NA     (TOKENS * 2)

typedef unsigned int   uint32;
typedef unsigned short u16;
typedef __bf16 bf16x8 __attribute__((ext_vector_type(8)));
typedef float  f32x4  __attribute__((ext_vector_type(4)));

__device__ __forceinline__ u16 f2bf(float f) {
    union { float f; uint32 u; } v; v.f = f;
    return (u16)((v.u + 0x7fffu + ((v.u >> 16) & 1u)) >> 16);
}
// 16B-unit index into a 64x64 bf16 LDS tile, XOR-swizzled to kill bank conflicts
__device__ __forceinline__ int swz(int row, int k8) { return row * 8 + (k8 ^ (row & 7)); }

__device__ __forceinline__ uint4 cvt8(float4 a, float4 b) {
    union { uint4 v; u16 h[8]; } o;
    o.h[0] = f2bf(a.x); o.h[1] = f2bf(a.y); o.h[2] = f2bf(a.z); o.h[3] = f2bf(a.w);
    o.h[4] = f2bf(b.x); o.h[5] = f2bf(b.y); o.h[6] = f2bf(b.z); o.h[7] = f2bf(b.w);
    return o.v;
}

// ---------------- X: fp32 -> bf16 once ----------------
__global__ void xcvt_kernel(const float* __restrict__ X, u16* __restrict__ Xb) {
    const int gid = blockIdx.x * 256 + threadIdx.x;   // 8 elements per thread
    const float4* s = (const float4*)X + (size_t)gid * 2;
    ((uint4*)Xb)[gid] = cvt8(s[0], s[1]);
}

// ---------------- routing: bucket assignment ids by expert ----------------
__global__ void route_kernel(const int* __restrict__ idx, int* __restrict__ off,
                             int* __restrict__ bucket) {
    __shared__ int scnt[NEXP];
    __shared__ int soff[NEXP + 1];
    __shared__ int sfill[NEXP];
    __shared__ int sflag;
    const int tid = threadIdx.x;
    if (tid < NEXP) { scnt[tid] = 0; sfill[tid] = 0; }
    if (tid == 0) sflag = 0;
    __syncthreads();
    // int64-vs-int32 probe: if buffer is int64, every odd int32 word is a zero
    // high-word. Probe first NA/2 elements (in-bounds under both layouts).
    int any = 0;
    for (int a = tid; a < NA / 2; a += 256) any |= idx[2 * a + 1];
    if (any) atomicOr(&sflag, 1);
    __syncthreads();
    const int stride = sflag ? 1 : 2;
    for (int a = tid; a < NA; a += 256) atomicAdd(&scnt[idx[a * stride]], 1);
    __syncthreads();
    if (tid == 0) {
        int s = 0;
        for (int e = 0; e < NEXP; ++e) { soff[e] = s; s += scnt[e]; }
        soff[NEXP] = s;
    }
    __syncthreads();
    for (int a = tid; a < NA; a += 256) {
        int e = idx[a * stride];
        int slot = atomicAdd(&sfill[e], 1);
        bucket[soff[e] + slot] = a;   // assignment id; token = a>>1
    }
    if (tid <= NEXP) off[tid] = soff[tid];
}

// ---------------- GEMM1: gate/up + SwiGLU -> H (slot-ordered, bf16) ----------------
__global__ __launch_bounds__(256) void gemm1_kernel(
    const u16* __restrict__ Xb,  // [TOKENS, HIDDEN] bf16
    const float* __restrict__ Wg,  // [NEXP, INTER, HIDDEN] fp32
    const float* __restrict__ Wu,  // [NEXP, INTER, HIDDEN] fp32
    const int* __restrict__ off, const int* __restrict__ bucket,
    u16* __restrict__ Hbuf)      // [NA, INTER] bf16, slot-ordered
{
    const int e    = blockIdx.y;
    const int j0   = blockIdx.x * 64;
    const int base = off[e];
    const int ne   = off[e + 1] - base;
    if (ne <= 0) return;

    __shared__ u16 Xs[64 * 64];
    __shared__ u16 Gs[64 * 64];
    __shared__ u16 Us[64 * 64];

    const int tid  = threadIdx.x;
    const int lane = tid & 63;
    const int wave = tid >> 6;
    const int wm = (wave & 1) * 32;
    const int wn = (wave >> 1) * 32;
    const int lr = lane & 15;
    const int lq = lane >> 4;
    const int lrow = tid >> 3;   // 0..31
    const int lc8  = tid & 7;    // 0..7 (8-element chunk)

    for (int m0 = 0; m0 < ne; m0 += 64) {
        int tok[2];
#pragma unroll
        for (int it = 0; it < 2; ++it) {
            int slot = m0 + lrow + it * 32;
            slot = slot < ne ? slot : ne - 1;
            tok[it] = bucket[base + slot] >> 1;
        }
        f32x4 ag[2][2] = {};
        f32x4 au[2][2] = {};
        for (int k0 = 0; k0 < HIDDEN; k0 += 64) {
            __syncthreads();
#pragma unroll
            for (int it = 0; it < 2; ++it) {
                const int row = lrow + it * 32;
                const uint4 vx = *(const uint4*)(Xb + (size_t)tok[it] * HIDDEN + k0 + lc8 * 8);
                *(uint4*)(Xs + swz(row, lc8) * 8) = vx;
                const size_t wrow = ((size_t)e * INTER + j0 + row) * HIDDEN + k0 + lc8 * 8;
                const float4* gp = (const float4*)(Wg + wrow);
                *(uint4*)(Gs + swz(row, lc8) * 8) = cvt8(gp[0], gp[1]);
                const float4* up = (const float4*)(Wu + wrow);
                *(uint4*)(Us + swz(row, lc8) * 8) = cvt8(up[0], up[1]);
            }
            __syncthreads();
#pragma unroll
            for (int kk = 0; kk < 2; ++kk) {
                const int k8 = kk * 4 + lq;
                bf16x8 af[2], bg[2], bu[2];
#pragma unroll
                for (int i = 0; i < 2; ++i) {
                    af[i] = *(const bf16x8*)(Xs + swz(wm + i * 16 + lr, k8) * 8);
                    bg[i] = *(const bf16x8*)(Gs + swz(wn + i * 16 + lr, k8) * 8);
                    bu[i] = *(const bf16x8*)(Us + swz(wn + i * 16 + lr, k8) * 8);
                }
#pragma unroll
                for (int i = 0; i < 2; ++i)
#pragma unroll
                    for (int j = 0; j < 2; ++j) {
                        ag[i][j] = __builtin_amdgcn_mfma_f32_16x16x32_bf16(af[i], bg[j], ag[i][j], 0, 0, 0);
                        au[i][j] = __builtin_amdgcn_mfma_f32_16x16x32_bf16(af[i], bu[j], au[i][j], 0, 0, 0);
                    }
            }
        }
        // epilogue: h = silu(g)*u  (C layout: col=lane&15, row=(lane>>4)*4+reg)
#pragma unroll
        for (int i = 0; i < 2; ++i)
#pragma unroll
            for (int j = 0; j < 2; ++j)
#pragma unroll
                for (int r = 0; r < 4; ++r) {
                    const int row  = wm + i * 16 + lq * 4 + r;
                    const int slot = m0 + row;
                    if (slot < ne) {
                        const float g = ag[i][j][r];
                        const float u = au[i][j][r];
                        const float h = (g / (1.f + __expf(-g))) * u;
                        Hbuf[(size_t)(base + slot) * INTER + j0 + wn + j * 16 + lr] = f2bf(h);
                    }
                }
    }
}

// ---------------- GEMM2: down-proj -> atomicAdd into out ----------------
__global__ __launch_bounds__(256) void gemm2_kernel(
    const u16* __restrict__ Hbuf,   // [NA, INTER] bf16, slot-ordered
    const float* __restrict__ Wd,   // [NEXP, HIDDEN, INTER] fp32
    const float* __restrict__ tkw,  // [TOKENS, 2] fp32
    const int* __restrict__ off, const int* __restrict__ bucket,
    float* __restrict__ out)        // [TOKENS, HIDDEN] fp32, pre-zeroed
{
    const int e    = blockIdx.y;
    const int n0   = blockIdx.x * 64;
    const int base = off[e];
    const int ne   = off[e + 1] - base;
    if (ne <= 0) return;

    __shared__ u16 Hs[64 * 64];
    __shared__ u16 Ds[64 * 64];

    const int tid  = threadIdx.x;
    const int lane = tid & 63;
    const int wave = tid >> 6;
    const int wm = (wave & 1) * 32;
    const int wn = (wave >> 1) * 32;
    const int lr = lane & 15;
    const int lq = lane >> 4;
    const int lrow = tid >> 3;
    const int lc8  = tid & 7;

    for (int m0 = 0; m0 < ne; m0 += 64) {
        f32x4 ac[2][2] = {};
        for (int k0 = 0; k0 < INTER; k0 += 64) {
            __syncthreads();
#pragma unroll
            for (int it = 0; it < 2; ++it) {
                const int row = lrow + it * 32;
                int slot = m0 + row;
                slot = slot < ne ? slot : ne - 1;
                const uint4 vh = *(const uint4*)(Hbuf + (size_t)(base + slot) * INTER + k0 + lc8 * 8);
                *(uint4*)(Hs + swz(row, lc8) * 8) = vh;
                const float4* dp = (const float4*)(Wd + ((size_t)e * HIDDEN + n0 + row) * INTER + k0 + lc8 * 8);
                *(uint4*)(Ds + swz(row, lc8) * 8) = cvt8(dp[0], dp[1]);
            }
            __syncthreads();
#pragma unroll
            for (int kk = 0; kk < 2; ++kk) {
                const int k8 = kk * 4 + lq;
                bf16x8 af[2], bd[2];
#pragma unroll
                for (int i = 0; i < 2; ++i) {
                    af[i] = *(const bf16x8*)(Hs + swz(wm + i * 16 + lr, k8) * 8);
                    bd[i] = *(const bf16x8*)(Ds + swz(wn + i * 16 + lr, k8) * 8);
                }
#pragma unroll
                for (int i = 0; i < 2; ++i)
#pragma unroll
                    for (int j = 0; j < 2; ++j)
                        ac[i][j] = __builtin_amdgcn_mfma_f32_16x16x32_bf16(af[i], bd[j], ac[i][j], 0, 0, 0);
            }
        }
#pragma unroll
        for (int i = 0; i < 2; ++i)
#pragma unroll
            for (int r = 0; r < 4; ++r) {
                const int row  = wm + i * 16 + lq * 4 + r;
                const int slot = m0 + row;
                if (slot < ne) {
                    const int a = bucket[base + slot];
                    const int t = a >> 1;
                    const float w = tkw[a];
#pragma unroll
                    for (int j = 0; j < 2; ++j)
                        atomicAdd(out + (size_t)t * HIDDEN + n0 + wn + j * 16 + lr,
                                  w * ac[i][j][r]);
                }
            }
    }
}

extern "C" void kernel_launch(void* const* d_in, const int* in_sizes, int n_in,
                              void* d_out, int out_size, void* d_ws, size_t ws_size,
                              hipStream_t stream) {
    const float* X   = (const float*)d_in[0];   // [2048,2048] fp32
    const int*   idx = (const int*)d_in[1];     // [2048,2] int
    const float* tkw = (const float*)d_in[2];   // [2048,2] fp32
    const float* Wg  = (const float*)d_in[3];   // [16,768,2048] fp32
    const float* Wu  = (const float*)d_in[4];   // [16,768,2048] fp32
    const float* Wd  = (const float*)d_in[5];   // [16,2048,768] fp32
    float* out = (float*)d_out;

    char* ws = (char*)d_ws;
    int* off    = (int*)ws;                     // 17 ints
    int* bucket = (int*)(ws + 128);             // 4096 ints
    u16* Xb     = (u16*)(ws + 32768);           // 2048*2048 bf16 = 8.39 MB
    u16* Hbuf   = (u16*)(ws + 32768 + (size_t)TOKENS * HIDDEN * 2);  // 4096*768 bf16 = 6.29 MB

    hipMemsetAsync(out, 0, (size_t)TOKENS * HIDDEN * sizeof(float), stream);
    xcvt_kernel<<<TOKENS * HIDDEN / 8 / 256, 256, 0, stream>>>(X, Xb);
    route_kernel<<<1, 256, 0, stream>>>(idx, off, bucket);
    dim3 g1(INTER / 64, NEXP);
    gemm1_kernel<<<g1, 256, 0, stream>>>(Xb, Wg, Wu, off, bucket, Hbuf);
    dim3 g2(HIDDEN / 64, NEXP);
    gemm2_kernel<<<g2, 256, 0, stream>>>(Hbuf, Wd, tkw, off, bucket, out);
}

// Round 3
// 379.273 us; speedup vs baseline: 2.0556x; 2.0556x over previous
//
#include <hip/hip_runtime.h>

#define TOKENS 2048
#define HIDDEN 2048
#define INTER  768
#define NEXP   16
#define NA     (TOKENS * 2)
#define MTILE  128
#define MAXT   64

typedef unsigned int   uint32;
typedef unsigned short u16;
typedef __bf16 bf16x8 __attribute__((ext_vector_type(8)));
typedef float  f32x4  __attribute__((ext_vector_type(4)));

__device__ __forceinline__ u16 f2bf(float f) {
    union { float f; uint32 u; } v; v.f = f;
    return (u16)((v.u + 0x7fffu + ((v.u >> 16) & 1u)) >> 16);
}
// fast pack of two fp32 -> two bf16 (round-half-away; plenty for 2% threshold)
__device__ __forceinline__ uint32 pk2(float a, float b) {
    union { float f; uint32 u; } x, y; x.f = a; y.f = b;
    return ((x.u + 0x8000u) >> 16) | ((y.u + 0x8000u) & 0xffff0000u);
}
__device__ __forceinline__ uint4 cvt8f(float4 a, float4 b) {
    uint4 o;
    o.x = pk2(a.x, a.y); o.y = pk2(a.z, a.w);
    o.z = pk2(b.x, b.y); o.w = pk2(b.z, b.w);
    return o;
}
// 16B-unit index into a row-major (rowstride 64 bf16) LDS tile, XOR-swizzled
__device__ __forceinline__ int swz(int row, int k8) { return row * 8 + (k8 ^ (row & 7)); }

// ---------------- X: fp32 -> bf16 once ----------------
__global__ void xcvt_kernel(const float* __restrict__ X, u16* __restrict__ Xb) {
    const int gid = blockIdx.x * 256 + threadIdx.x;
    const float4* s = (const float4*)X + (size_t)gid * 2;
    ((uint4*)Xb)[gid] = cvt8f(s[0], s[1]);
}

// ---------------- routing: bucket assignments, emit m-tile list ----------------
__global__ void route_kernel(const int* __restrict__ idx, int* __restrict__ meta,
                             int* __restrict__ bucket) {
    __shared__ int scnt[NEXP];
    __shared__ int soff[NEXP + 1];
    __shared__ int sfill[NEXP];
    __shared__ int sflag;
    const int tid = threadIdx.x;
    if (tid < NEXP) { scnt[tid] = 0; sfill[tid] = 0; }
    if (tid == 0) sflag = 0;
    __syncthreads();
    // int64-vs-int32 probe: int64 buffer has all-zero odd words
    int any = 0;
    for (int a = tid; a < NA / 2; a += 256) any |= idx[2 * a + 1];
    if (any) atomicOr(&sflag, 1);
    __syncthreads();
    const int stride = sflag ? 1 : 2;
    for (int a = tid; a < NA; a += 256) atomicAdd(&scnt[idx[a * stride]], 1);
    __syncthreads();
    if (tid == 0) {
        int s = 0;
        for (int e = 0; e < NEXP; ++e) { soff[e] = s; s += scnt[e]; }
        soff[NEXP] = s;
        int nt = 0;
        for (int e = 0; e < NEXP; ++e) {
            const int ne = soff[e + 1] - soff[e];
            for (int m0 = 0; m0 < ne; m0 += MTILE) {
                meta[32 + nt] = e;      // tile expert
                meta[96 + nt] = m0;     // tile m0
                ++nt;
            }
        }
        meta[17] = nt;
    }
    __syncthreads();
    for (int a = tid; a < NA; a += 256) {
        int e = idx[a * stride];
        int slot = atomicAdd(&sfill[e], 1);
        bucket[soff[e] + slot] = a;   // assignment id; token = a>>1
    }
    if (tid <= NEXP) meta[tid] = soff[tid];
}

// ---------------- GEMM1: gate/up + SwiGLU -> H (slot-ordered, bf16) ----------------
// block: 128 slots x 64 inter-cols; wave w: rows [w*32, w*32+32)
__global__ __launch_bounds__(256, 3) void gemm1_kernel(
    const u16* __restrict__ Xb,    // [TOKENS, HIDDEN] bf16
    const float* __restrict__ Wg,  // [NEXP, INTER, HIDDEN] fp32
    const float* __restrict__ Wu,  // [NEXP, INTER, HIDDEN] fp32
    const int* __restrict__ meta, const int* __restrict__ bucket,
    u16* __restrict__ Hbuf)        // [NA, INTER] bf16, slot-ordered
{
    const int ty = blockIdx.y;
    if (ty >= meta[17]) return;
    const int e    = meta[32 + ty];
    const int m0   = meta[96 + ty];
    const int j0   = blockIdx.x * 64;
    const int base = meta[e];
    const int ne   = meta[e + 1] - base;

    __shared__ u16 Xs[MTILE * 64];
    __shared__ u16 Gs[64 * 64];
    __shared__ u16 Us[64 * 64];

    const int tid  = threadIdx.x;
    const int lane = tid & 63;
    const int wm   = (tid >> 6) * 32;
    const int lr   = lane & 15;
    const int lq   = lane >> 4;
    const int srow = tid >> 3;    // 0..31 staging row
    const int lc8  = tid & 7;     // 0..7  staging 16B chunk

    int tok[4];
#pragma unroll
    for (int p = 0; p < 4; ++p) {
        int slot = m0 + srow + p * 32;
        slot = slot < ne ? slot : ne - 1;
        tok[p] = bucket[base + slot] >> 1;
    }

    f32x4 ag[2][4] = {};
    f32x4 au[2][4] = {};
    for (int k0 = 0; k0 < HIDDEN; k0 += 64) {
        __syncthreads();
#pragma unroll
        for (int p = 0; p < 4; ++p) {
            const int row = srow + p * 32;
            const uint4 vx = *(const uint4*)(Xb + (size_t)tok[p] * HIDDEN + k0 + lc8 * 8);
            *(uint4*)(Xs + swz(row, lc8) * 8) = vx;
        }
#pragma unroll
        for (int p = 0; p < 2; ++p) {
            const int row = srow + p * 32;
            const size_t wr = ((size_t)e * INTER + j0 + row) * HIDDEN + k0 + lc8 * 8;
            const float4* gp = (const float4*)(Wg + wr);
            *(uint4*)(Gs + swz(row, lc8) * 8) = cvt8f(gp[0], gp[1]);
            const float4* up = (const float4*)(Wu + wr);
            *(uint4*)(Us + swz(row, lc8) * 8) = cvt8f(up[0], up[1]);
        }
        __syncthreads();
#pragma unroll
        for (int kk = 0; kk < 2; ++kk) {
            const int k8 = kk * 4 + lq;
            bf16x8 af[2], bg[4], bu[4];
#pragma unroll
            for (int i = 0; i < 2; ++i)
                af[i] = *(const bf16x8*)(Xs + swz(wm + i * 16 + lr, k8) * 8);
#pragma unroll
            for (int j = 0; j < 4; ++j) {
                bg[j] = *(const bf16x8*)(Gs + swz(j * 16 + lr, k8) * 8);
                bu[j] = *(const bf16x8*)(Us + swz(j * 16 + lr, k8) * 8);
            }
#pragma unroll
            for (int i = 0; i < 2; ++i)
#pragma unroll
                for (int j = 0; j < 4; ++j) {
                    ag[i][j] = __builtin_amdgcn_mfma_f32_16x16x32_bf16(af[i], bg[j], ag[i][j], 0, 0, 0);
                    au[i][j] = __builtin_amdgcn_mfma_f32_16x16x32_bf16(af[i], bu[j], au[i][j], 0, 0, 0);
                }
        }
    }
    // epilogue: h = silu(g)*u ; C layout col=lane&15, row=lq*4+r
#pragma unroll
    for (int i = 0; i < 2; ++i)
#pragma unroll
        for (int r = 0; r < 4; ++r) {
            const int slot = m0 + wm + i * 16 + lq * 4 + r;
            if (slot < ne) {
#pragma unroll
                for (int j = 0; j < 4; ++j) {
                    const float g = ag[i][j][r];
                    const float u = au[i][j][r];
                    const float h = (g / (1.f + __expf(-g))) * u;
                    Hbuf[(size_t)(base + slot) * INTER + j0 + j * 16 + lr] = f2bf(h);
                }
            }
        }
}

// ---------------- GEMM2: down-proj -> weighted atomicAdd into out ----------------
__global__ __launch_bounds__(256, 3) void gemm2_kernel(
    const u16* __restrict__ Hbuf,   // [NA, INTER] bf16, slot-ordered
    const float* __restrict__ Wd,   // [NEXP, HIDDEN, INTER] fp32
    const float* __restrict__ tkw,  // [TOKENS, 2] fp32
    const int* __restrict__ meta, const int* __restrict__ bucket,
    float* __restrict__ out)        // [TOKENS, HIDDEN] fp32, pre-zeroed
{
    const int ty = blockIdx.y;
    if (ty >= meta[17]) return;
    const int e    = meta[32 + ty];
    const int m0   = meta[96 + ty];
    const int n0   = blockIdx.x * 64;
    const int base = meta[e];
    const int ne   = meta[e + 1] - base;

    __shared__ u16 Hs[MTILE * 64];
    __shared__ u16 Ds[64 * 64];

    const int tid  = threadIdx.x;
    const int lane = tid & 63;
    const int wm   = (tid >> 6) * 32;
    const int lr   = lane & 15;
    const int lq   = lane >> 4;
    const int srow = tid >> 3;
    const int lc8  = tid & 7;

    int sl[4];
#pragma unroll
    for (int p = 0; p < 4; ++p) {
        int slot = m0 + srow + p * 32;
        sl[p] = slot < ne ? slot : ne - 1;
    }

    f32x4 ac[2][4] = {};
    for (int k0 = 0; k0 < INTER; k0 += 64) {
        __syncthreads();
#pragma unroll
        for (int p = 0; p < 4; ++p) {
            const int row = srow + p * 32;
            const uint4 vh = *(const uint4*)(Hbuf + (size_t)(base + sl[p]) * INTER + k0 + lc8 * 8);
            *(uint4*)(Hs + swz(row, lc8) * 8) = vh;
        }
#pragma unroll
        for (int p = 0; p < 2; ++p) {
            const int row = srow + p * 32;
            const float4* dp = (const float4*)(Wd + ((size_t)e * HIDDEN + n0 + row) * INTER + k0 + lc8 * 8);
            *(uint4*)(Ds + swz(row, lc8) * 8) = cvt8f(dp[0], dp[1]);
        }
        __syncthreads();
#pragma unroll
        for (int kk = 0; kk < 2; ++kk) {
            const int k8 = kk * 4 + lq;
            bf16x8 af[2], bd[4];
#pragma unroll
            for (int i = 0; i < 2; ++i)
                af[i] = *(const bf16x8*)(Hs + swz(wm + i * 16 + lr, k8) * 8);
#pragma unroll
            for (int j = 0; j < 4; ++j)
                bd[j] = *(const bf16x8*)(Ds + swz(j * 16 + lr, k8) * 8);
#pragma unroll
            for (int i = 0; i < 2; ++i)
#pragma unroll
                for (int j = 0; j < 4; ++j)
                    ac[i][j] = __builtin_amdgcn_mfma_f32_16x16x32_bf16(af[i], bd[j], ac[i][j], 0, 0, 0);
        }
    }
#pragma unroll
    for (int i = 0; i < 2; ++i)
#pragma unroll
        for (int r = 0; r < 4; ++r) {
            const int slot = m0 + wm + i * 16 + lq * 4 + r;
            if (slot < ne) {
                const int a = bucket[base + slot];
                const int t = a >> 1;
                const float w = tkw[a];
#pragma unroll
                for (int j = 0; j < 4; ++j)
                    atomicAdd(out + (size_t)t * HIDDEN + n0 + j * 16 + lr, w * ac[i][j][r]);
            }
        }
}

extern "C" void kernel_launch(void* const* d_in, const int* in_sizes, int n_in,
                              void* d_out, int out_size, void* d_ws, size_t ws_size,
                              hipStream_t stream) {
    const float* X   = (const float*)d_in[0];
    const int*   idx = (const int*)d_in[1];
    const float* tkw = (const float*)d_in[2];
    const float* Wg  = (const float*)d_in[3];
    const float* Wu  = (const float*)d_in[4];
    const float* Wd  = (const float*)d_in[5];
    float* out = (float*)d_out;

    char* ws = (char*)d_ws;
    int* meta   = (int*)ws;                     // off[0..16], ntiles[17], tileE[32..], tileM0[96..]
    int* bucket = (int*)(ws + 1024);            // 4096 ints
    u16* Xb     = (u16*)(ws + 32768);           // 8.39 MB
    u16* Hbuf   = (u16*)(ws + 32768 + (size_t)TOKENS * HIDDEN * 2);  // 6.29 MB

    hipMemsetAsync(out, 0, (size_t)TOKENS * HIDDEN * sizeof(float), stream);
    xcvt_kernel<<<TOKENS * HIDDEN / 8 / 256, 256, 0, stream>>>(X, Xb);
    route_kernel<<<1, 256, 0, stream>>>(idx, meta, bucket);
    dim3 g1(INTER / 64, MAXT);
    gemm1_kernel<<<g1, 256, 0, stream>>>(Xb, Wg, Wu, meta, bucket, Hbuf);
    dim3 g2(HIDDEN / 64, MAXT);
    gemm2_kernel<<<g2, 256, 0, stream>>>(Hbuf, Wd, tkw, meta, bucket, out);
}